// Round 1
// baseline (820.158 us; speedup 1.0000x reference)
//
#include <hip/hip_runtime.h>
#include <math.h>

#define NTOK 32768
#define HH 32
#define DD 64
#define WPB 4          // waves per block
#define BLOCK (WPB * 64)
#define GRID 1024      // 4096 waves -> 8 tokens per wave

__device__ __forceinline__ float rsum64(float v) {
    v += __shfl_xor(v, 32);
    v += __shfl_xor(v, 16);
    v += __shfl_xor(v, 8);
    v += __shfl_xor(v, 4);
    v += __shfl_xor(v, 2);
    v += __shfl_xor(v, 1);
    return v;
}

__device__ __forceinline__ float tanh_fast(float x) {
    float ax = fabsf(x);
    float t = __expf(-2.0f * ax);
    float r = (1.0f - t) / (1.0f + t);
    return copysignf(r, x);
}

__device__ __forceinline__ float atanh_fast(float x) {
    return 0.5f * __logf((1.0f + x) / (1.0f - x));
}

__global__ __launch_bounds__(BLOCK, 2) void hyp_attn_kernel(
    const float* __restrict__ cur,   // [N, D]
    const float* __restrict__ hist,  // [H, N, D]
    const float* __restrict__ curv,  // [1]
    const float* __restrict__ Wq,    // [D, D]
    const float* __restrict__ bq,    // [D]
    const float* __restrict__ Wk,    // [D, D]
    const float* __restrict__ bk,    // [D]
    const float* __restrict__ av,    // [D, 1]
    float* __restrict__ out,         // [N, D]
    int nWaves)
{
    // Wq transposed with +1 row pad: wqT[d*65 + e] = Wq[e*64 + d]
    // read pattern in matvec: addr = d*65 + lane -> bank (d+lane)%32, 2-way (free)
    __shared__ float wqT[DD * 65];
    __shared__ float th_lds[WPB][HH][DD];  // tangent history, one slab per wave
    __shared__ float tc_lds[WPB][DD];      // tangent current

    const int tid  = threadIdx.x;
    const int lane = tid & 63;
    const int wv   = tid >> 6;

    // stage Wq^T into LDS (coalesced global read; LDS write bank = (d+e)%32, free)
    for (int idx = tid; idx < DD * DD; idx += BLOCK) {
        int e = idx >> 6, d = idx & 63;
        wqT[d * 65 + e] = Wq[idx];
    }

    // Wk row `lane` in registers (64 VGPRs); loaded once, L2-served
    float4 wkr[16];
    {
        const float4* p = (const float4*)(Wk + lane * DD);
#pragma unroll
        for (int j = 0; j < 16; ++j) wkr[j] = p[j];
    }
    const float bqv = bq[lane];
    const float bkv = bk[lane];
    const float avv = av[lane];
    const float c   = curv[0];
    const float sc  = sqrtf(c);
    __syncthreads();

    const int gw = blockIdx.x * WPB + wv;
    for (int n = gw; n < NTOK; n += nWaves) {
        // ---- tangent_current = logmap0(current_emb[n]) ----
        float y  = cur[n * DD + lane];
        float r2 = rsum64(y * y);
        float scr = sc * sqrtf(r2);
        float f = (scr > 1e-12f) ? (2.0f * atanh_fast(scr) / scr) : 2.0f;
        float tcv = f * y;
        tc_lds[wv][lane] = tcv;

        // ---- query[e] = sum_d tc[d] * Wq[e,d] + bq[e] ----
        float q = bqv;
#pragma unroll 16
        for (int d = 0; d < DD; ++d) {
            q = fmaf(tc_lds[wv][d], wqT[d * 65 + lane], q);
        }

        // ---- history pass: tangent, key matvec, score; th cached in LDS ----
        float sraw = -INFINITY;  // lane h will hold raw score s[h] (h < 32)
        float yh = hist[(size_t)n * DD + lane];  // h = 0, prefetched
        for (int h = 0; h < HH; ++h) {
            float ynext = 0.0f;
            if (h + 1 < HH)
                ynext = hist[((size_t)(h + 1) * NTOK + n) * DD + lane];

            float rr2 = rsum64(yh * yh);
            float rr  = sc * sqrtf(rr2);
            float fh  = (rr > 1e-12f) ? (2.0f * atanh_fast(rr) / rr) : 2.0f;
            float th  = fh * yh;
            th_lds[wv][h][lane] = th;

            // key[e] = sum_d Wk[e,d] * th[d] + bk[e]; th broadcast via b128 (free)
            float k0 = bkv, k1 = 0.0f, k2 = 0.0f, k3 = 0.0f;
            const float4* t4 = (const float4*)(&th_lds[wv][h][0]);
#pragma unroll
            for (int j = 0; j < 16; ++j) {
                float4 t = t4[j];
                k0 = fmaf(wkr[j].x, t.x, k0);
                k1 = fmaf(wkr[j].y, t.y, k1);
                k2 = fmaf(wkr[j].z, t.z, k2);
                k3 = fmaf(wkr[j].w, t.w, k3);
            }
            float key = (k0 + k1) + (k2 + k3);

            float s  = tanh_fast(q + key) * avv;
            float sh = rsum64(s);
            sraw = (lane == h) ? sh : sraw;
            yh = ynext;
        }

        // ---- softmax over h (lanes 0..31 hold s[h]; 32..63 = -inf) ----
        float m = sraw;
        m = fmaxf(m, __shfl_xor(m, 16));
        m = fmaxf(m, __shfl_xor(m, 8));
        m = fmaxf(m, __shfl_xor(m, 4));
        m = fmaxf(m, __shfl_xor(m, 2));
        m = fmaxf(m, __shfl_xor(m, 1));
        float ev = (lane < HH) ? __expf(sraw - m) : 0.0f;
        float esum = ev;
        esum += __shfl_xor(esum, 16);
        esum += __shfl_xor(esum, 8);
        esum += __shfl_xor(esum, 4);
        esum += __shfl_xor(esum, 2);
        esum += __shfl_xor(esum, 1);
        float w = ev / esum;  // lane h: softmax weight for history slot h

        // ---- weighted sum over h ----
        float ws = 0.0f;
#pragma unroll
        for (int h = 0; h < HH; ++h) {
            float wh = __shfl(w, h);  // broadcast from lane h
            ws = fmaf(wh, th_lds[wv][h][lane], ws);
        }

        // ---- context = expmap0(ws) ----
        float vn2 = rsum64(ws * ws);
        float vn  = sc * sqrtf(vn2);
        float f2  = (vn > 1e-12f) ? (tanh_fast(0.5f * vn) / vn) : 0.5f;
        out[n * DD + lane] = f2 * ws;
    }
}

extern "C" void kernel_launch(void* const* d_in, const int* in_sizes, int n_in,
                              void* d_out, int out_size, void* d_ws, size_t ws_size,
                              hipStream_t stream) {
    const float* cur  = (const float*)d_in[0];
    const float* hist = (const float*)d_in[1];
    const float* curv = (const float*)d_in[2];
    const float* Wq   = (const float*)d_in[3];
    const float* bq   = (const float*)d_in[4];
    const float* Wk   = (const float*)d_in[5];
    const float* bk   = (const float*)d_in[6];
    const float* av   = (const float*)d_in[7];
    float* out = (float*)d_out;

    int nWaves = GRID * WPB;
    hipLaunchKernelGGL(hyp_attn_kernel, dim3(GRID), dim3(BLOCK), 0, stream,
                       cur, hist, curv, Wq, bq, Wk, bk, av, out, nWaves);
}

// Round 2
// 391.966 us; speedup vs baseline: 2.0924x; 2.0924x over previous
//
#include <hip/hip_runtime.h>
#include <math.h>

#define NTOK 32768
#define HH 32
#define DD 64
#define TTOK 32              // tokens per block
#define NBLK (NTOK / TTOK)   // 1024 blocks

typedef float f4 __attribute__((ext_vector_type(4)));
typedef short bf16x8 __attribute__((ext_vector_type(8)));

__device__ __forceinline__ float rcpf_(float x) { return __builtin_amdgcn_rcpf(x); }

// tanh via exp + hw rcp (~7 instr); clamp avoids inf/inf NaN
__device__ __forceinline__ float tanh_f(float x) {
    x = fminf(fmaxf(x, -15.f), 15.f);
    float t = __expf(x + x);
    return (t - 1.f) * rcpf_(t + 1.f);
}

// log-map scale: 2*atanh(x)/x = ln((1+x)/(1-x))/x ; -> 2 as x->0
__device__ __forceinline__ float logmap_f(float x) {
    float u = __logf((1.f + x) * rcpf_(1.f - x));
    return (x > 1e-4f) ? u * rcpf_(x) : 2.f;
}

// pack 8 floats -> bf16 hi parts (truncate; residual captured exactly by lo8)
__device__ __forceinline__ bf16x8 hi8(f4 a, f4 b) {
    bf16x8 r;
#pragma unroll
    for (int j = 0; j < 4; ++j) {
        r[j]     = (short)(__float_as_uint(a[j]) >> 16);
        r[j + 4] = (short)(__float_as_uint(b[j]) >> 16);
    }
    return r;
}
__device__ __forceinline__ bf16x8 lo8(f4 a, f4 b) {
    bf16x8 r;
#pragma unroll
    for (int j = 0; j < 4; ++j) {
        float ah = __uint_as_float(__float_as_uint(a[j]) & 0xFFFF0000u);
        float bh = __uint_as_float(__float_as_uint(b[j]) & 0xFFFF0000u);
        r[j]     = (short)(__float_as_uint(a[j] - ah) >> 16);
        r[j + 4] = (short)(__float_as_uint(b[j] - bh) >> 16);
    }
    return r;
}

// Load 32-token tile rows for this lane in MFMA-A layout and apply log-map.
// lane owns: tokA = lane&15 (A-tile tt=0), tokB = 16+(lane&15) (tt=1),
// d-octets {8q, 32+8q} (q = lane>>4) == A[m=lane&15][k=quad*8+j] for K-steps s=0,1.
__device__ __forceinline__ void load_tangent(const float* base, int lane15, int quad,
                                             float sc, f4 yv[8]) {
    const float* rA = base + lane15 * DD + 8 * quad;
    const float* rB = base + (16 + lane15) * DD + 8 * quad;
    yv[0] = *(const f4*)(rA);
    yv[1] = *(const f4*)(rA + 4);
    yv[2] = *(const f4*)(rA + 32);
    yv[3] = *(const f4*)(rA + 36);
    yv[4] = *(const f4*)(rB);
    yv[5] = *(const f4*)(rB + 4);
    yv[6] = *(const f4*)(rB + 32);
    yv[7] = *(const f4*)(rB + 36);
    f4 sA4 = yv[0]*yv[0] + yv[1]*yv[1] + yv[2]*yv[2] + yv[3]*yv[3];
    f4 sB4 = yv[4]*yv[4] + yv[5]*yv[5] + yv[6]*yv[6] + yv[7]*yv[7];
    float nA = sA4[0] + sA4[1] + sA4[2] + sA4[3];
    float nB = sB4[0] + sB4[1] + sB4[2] + sB4[3];
    // lanes l, l^16, l^32, l^48 hold the 4 d-quadrants of the same tokens
    nA += __shfl_xor(nA, 16); nA += __shfl_xor(nA, 32);
    nB += __shfl_xor(nB, 16); nB += __shfl_xor(nB, 32);
    float fA = logmap_f(sc * sqrtf(nA));
    float fB = logmap_f(sc * sqrtf(nB));
#pragma unroll
    for (int k = 0; k < 4; ++k) { yv[k] = yv[k] * fA; yv[k + 4] = yv[k + 4] * fB; }
}

// B-frags from row-major W[e][k]: lane holds W[e=16*et+(lane&15)][k=32*s+8*quad+j]
__device__ __forceinline__ void load_bfrags(const float* W, int lane15, int quad,
                                            bf16x8 Bh[4][2], bf16x8 Bl[4][2]) {
#pragma unroll
    for (int et = 0; et < 4; ++et)
#pragma unroll
        for (int s = 0; s < 2; ++s) {
            const f4* p = (const f4*)(W + (16 * et + lane15) * DD + 32 * s + 8 * quad);
            f4 w0 = p[0], w1 = p[1];
            Bh[et][s] = hi8(w0, w1);
            Bl[et][s] = lo8(w0, w1);
        }
}

// acc[tt][et] += yv @ W^T  via 3-term bf16 split (hi*hi + hi*lo + lo*hi)
__device__ __forceinline__ void mm_accum(const f4 yv[8], const bf16x8 Bh[4][2],
                                         const bf16x8 Bl[4][2], f4 acc[2][4]) {
    bf16x8 Ah[2][2];
#pragma unroll
    for (int tt = 0; tt < 2; ++tt)
#pragma unroll
        for (int s = 0; s < 2; ++s)
            Ah[tt][s] = hi8(yv[tt * 4 + s * 2], yv[tt * 4 + s * 2 + 1]);
#pragma unroll
    for (int tt = 0; tt < 2; ++tt)
#pragma unroll
        for (int s = 0; s < 2; ++s)
#pragma unroll
            for (int et = 0; et < 4; ++et) {
                acc[tt][et] = __builtin_amdgcn_mfma_f32_16x16x32_bf16(Ah[tt][s], Bh[et][s], acc[tt][et], 0, 0, 0);
                acc[tt][et] = __builtin_amdgcn_mfma_f32_16x16x32_bf16(Ah[tt][s], Bl[et][s], acc[tt][et], 0, 0, 0);
            }
    bf16x8 Al[2][2];
#pragma unroll
    for (int tt = 0; tt < 2; ++tt)
#pragma unroll
        for (int s = 0; s < 2; ++s)
            Al[tt][s] = lo8(yv[tt * 4 + s * 2], yv[tt * 4 + s * 2 + 1]);
#pragma unroll
    for (int tt = 0; tt < 2; ++tt)
#pragma unroll
        for (int s = 0; s < 2; ++s)
#pragma unroll
            for (int et = 0; et < 4; ++et)
                acc[tt][et] = __builtin_amdgcn_mfma_f32_16x16x32_bf16(Al[tt][s], Bh[et][s], acc[tt][et], 0, 0, 0);
}

__global__ __launch_bounds__(256, 2) void hyp_attn_mfma(
    const float* __restrict__ cur, const float* __restrict__ hist,
    const float* __restrict__ curv, const float* __restrict__ Wq,
    const float* __restrict__ bq, const float* __restrict__ Wk,
    const float* __restrict__ bk, const float* __restrict__ av,
    float* __restrict__ out)
{
    __shared__ float q2[DD * 36];        // q2[e][tok], stride 36 (pad; b128-aligned)
    __shared__ float sExch[4][TTOK];     // per-wave score exchange
    __shared__ float mBuf[4][TTOK];
    __shared__ float lBuf[4][TTOK];
    __shared__ float oBuf[4][TTOK * 68]; // per-wave O partials, [tok][d] stride 68

    const int tid    = threadIdx.x;
    const int wv     = tid >> 6;
    const int lane   = tid & 63;
    const int lane15 = lane & 15;
    const int quad   = lane >> 4;
    const int bb     = blockIdx.x;

    const float c  = curv[0];
    const float sc = sqrtf(c);
    const f4 zero4 = {0.f, 0.f, 0.f, 0.f};

    // attn_vec in C-frag layout: e = 16*et + lane15
    float avC[4];
#pragma unroll
    for (int et = 0; et < 4; ++et) avC[et] = av[16 * et + lane15];

    // ---- q phase (wave 0): q2[e][tok] = (tc @ Wq^T)[tok,e] + bq[e] + bk[e]
    if (wv == 0) {
        bf16x8 Qh[4][2], Ql[4][2];
        load_bfrags(Wq, lane15, quad, Qh, Ql);
        f4 yv[8];
        load_tangent(cur + (size_t)bb * TTOK * DD, lane15, quad, sc, yv);
        f4 qacc[2][4];
#pragma unroll
        for (int tt = 0; tt < 2; ++tt)
#pragma unroll
            for (int et = 0; et < 4; ++et) qacc[tt][et] = zero4;
        mm_accum(yv, Qh, Ql, qacc);
        // C-frag: value at [tok = 16*tt + 4*quad + r][e = 16*et + lane15]
#pragma unroll
        for (int et = 0; et < 4; ++et) {
            float bias = bq[16 * et + lane15] + bk[16 * et + lane15];
#pragma unroll
            for (int tt = 0; tt < 2; ++tt) {
                f4 qv = qacc[tt][et] + bias;
                *(f4*)&q2[(16 * et + lane15) * 36 + 16 * tt + 4 * quad] = qv;
            }
        }
    }

    // Wk B-frags (all waves, registers)
    bf16x8 Bh[4][2], Bl[4][2];
    load_bfrags(Wk, lane15, quad, Bh, Bl);

    __syncthreads();

    // ---- flash-style online softmax over this wave's 8 history slots
    float mA = -3.0e38f, mB = -3.0e38f, lA = 0.f, lB = 0.f;
    f4 OA[4] = {zero4, zero4, zero4, zero4};
    f4 OB[4] = {zero4, zero4, zero4, zero4};

#pragma unroll 1
    for (int i = 0; i < 8; ++i) {
        const int h = wv * 8 + i;
        f4 yv[8];
        load_tangent(hist + ((size_t)h * NTOK + (size_t)bb * TTOK) * DD, lane15, quad, sc, yv);

        f4 acc[2][4];
#pragma unroll
        for (int tt = 0; tt < 2; ++tt)
#pragma unroll
            for (int et = 0; et < 4; ++et) acc[tt][et] = zero4;
        mm_accum(yv, Bh, Bl, acc);   // keys (no bias; folded into q2)

        // scores: s[tok] = sum_e tanh(q + key) * av[e]
        f4 sv0 = zero4, sv1 = zero4;
#pragma unroll
        for (int et = 0; et < 4; ++et)
#pragma unroll
            for (int tt = 0; tt < 2; ++tt) {
                f4 qv = *(const f4*)&q2[(16 * et + lane15) * 36 + 16 * tt + 4 * quad];
                f4 x = acc[tt][et] + qv;
                f4 tn;
#pragma unroll
                for (int r = 0; r < 4; ++r) tn[r] = tanh_f(x[r]);
                if (tt == 0) sv0 += tn * avC[et]; else sv1 += tn * avC[et];
            }
        // reduce over e-columns (lane15 bits)
#pragma unroll
        for (int st = 1; st < 16; st <<= 1)
#pragma unroll
            for (int r = 0; r < 4; ++r) {
                sv0[r] += __shfl_xor(sv0[r], st);
                sv1[r] += __shfl_xor(sv1[r], st);
            }
        // exchange: C-frag token ownership -> load-layout token ownership
        if (lane15 == 0) {
#pragma unroll
            for (int r = 0; r < 4; ++r) {
                sExch[wv][4 * quad + r]      = sv0[r];
                sExch[wv][16 + 4 * quad + r] = sv1[r];
            }
        }
        float sA = sExch[wv][lane15];       // same-wave DS is in-order
        float sB = sExch[wv][16 + lane15];

        float mAn = fmaxf(mA, sA), mBn = fmaxf(mB, sB);
        float aA = __expf(mA - mAn), pA = __expf(sA - mAn);
        float aB = __expf(mB - mBn), pB = __expf(sB - mBn);
        lA = lA * aA + pA; mA = mAn;
        lB = lB * aB + pB; mB = mBn;
#pragma unroll
        for (int k = 0; k < 4; ++k) {
            OA[k] = OA[k] * aA + yv[k] * pA;
            OB[k] = OB[k] * aB + yv[k + 4] * pB;
        }
    }

    // ---- cross-wave (m,l,O) combine
    if (quad == 0) {
        mBuf[wv][lane15] = mA; mBuf[wv][16 + lane15] = mB;
        lBuf[wv][lane15] = lA; lBuf[wv][16 + lane15] = lB;
    }
    __syncthreads();
    float MA = fmaxf(fmaxf(mBuf[0][lane15], mBuf[1][lane15]),
                     fmaxf(mBuf[2][lane15], mBuf[3][lane15]));
    float MB = fmaxf(fmaxf(mBuf[0][16 + lane15], mBuf[1][16 + lane15]),
                     fmaxf(mBuf[2][16 + lane15], mBuf[3][16 + lane15]));
    float bA = __expf(mA - MA), bB = __expf(mB - MB);
#pragma unroll
    for (int k = 0; k < 4; ++k) { OA[k] = OA[k] * bA; OB[k] = OB[k] * bB; }
    {
        float* oA = &oBuf[wv][lane15 * 68];
        float* oB = &oBuf[wv][(16 + lane15) * 68];
        *(f4*)(oA + 8 * quad)      = OA[0];
        *(f4*)(oA + 8 * quad + 4)  = OA[1];
        *(f4*)(oA + 32 + 8 * quad) = OA[2];
        *(f4*)(oA + 36 + 8 * quad) = OA[3];
        *(f4*)(oB + 8 * quad)      = OB[0];
        *(f4*)(oB + 8 * quad + 4)  = OB[1];
        *(f4*)(oB + 32 + 8 * quad) = OB[2];
        *(f4*)(oB + 36 + 8 * quad) = OB[3];
    }
    __syncthreads();

    // ---- final: thread t owns 8 contiguous d of token t>>3; coalesced store
    {
        const int tok = tid >> 3;
        const int d0  = (tid & 7) * 8;
        f4 o0 = zero4, o1 = zero4;
#pragma unroll
        for (int w = 0; w < 4; ++w) {
            o0 += *(const f4*)&oBuf[w][tok * 68 + d0];
            o1 += *(const f4*)&oBuf[w][tok * 68 + d0 + 4];
        }
        float M = fmaxf(fmaxf(mBuf[0][tok], mBuf[1][tok]),
                        fmaxf(mBuf[2][tok], mBuf[3][tok]));
        float L = lBuf[0][tok] * __expf(mBuf[0][tok] - M)
                + lBuf[1][tok] * __expf(mBuf[1][tok] - M)
                + lBuf[2][tok] * __expf(mBuf[2][tok] - M)
                + lBuf[3][tok] * __expf(mBuf[3][tok] - M);
        float rl = rcpf_(L);
        o0 = o0 * rl; o1 = o1 * rl;
        f4 sq = o0 * o0 + o1 * o1;
        float nv = sq[0] + sq[1] + sq[2] + sq[3];
        nv += __shfl_xor(nv, 1); nv += __shfl_xor(nv, 2); nv += __shfl_xor(nv, 4);
        float x = sc * sqrtf(nv);
        float g = (x > 1e-4f) ? tanh_f(0.5f * x) * rcpf_(x) : 0.5f;  // tanh(x/2)/x -> 0.5
        float* op = out + ((size_t)bb * TTOK + tok) * DD + d0;
        *(f4*)(op)     = o0 * g;
        *(f4*)(op + 4) = o1 * g;
    }
}

extern "C" void kernel_launch(void* const* d_in, const int* in_sizes, int n_in,
                              void* d_out, int out_size, void* d_ws, size_t ws_size,
                              hipStream_t stream) {
    const float* cur  = (const float*)d_in[0];
    const float* hist = (const float*)d_in[1];
    const float* curv = (const float*)d_in[2];
    const float* Wq   = (const float*)d_in[3];
    const float* bq   = (const float*)d_in[4];
    const float* Wk   = (const float*)d_in[5];
    const float* bk   = (const float*)d_in[6];
    const float* av   = (const float*)d_in[7];
    float* out = (float*)d_out;

    hipLaunchKernelGGL(hyp_attn_mfma, dim3(NBLK), dim3(256), 0, stream,
                       cur, hist, curv, Wq, bq, Wk, bk, av, out);
}